// Round 17
// baseline (143.418 us; speedup 1.0000x reference)
//
#include <hip/hip_runtime.h>
#include <hip/hip_bf16.h>
#include <stdint.h>

typedef short bf16x8 __attribute__((ext_vector_type(8)));
typedef float f32x4 __attribute__((ext_vector_type(4)));
typedef unsigned int u32x2 __attribute__((ext_vector_type(2)));

__device__ __forceinline__ uint32_t pack2f(float lo, float hi) {
  union { __hip_bfloat162 h; uint32_t u; } c;
  c.h.x = __float2bfloat16(lo);
  c.h.y = __float2bfloat16(hi);
  return c.u;
}

__device__ __forceinline__ unsigned short f32_to_bf16(float f) {
  union { __hip_bfloat16 h; unsigned short u; } c;
  c.h = __float2bfloat16(f);
  return c.u;
}

__device__ __forceinline__ float bfbits_to_f32(uint32_t hi16) {
  union { uint32_t u; float f; } c;
  c.u = hi16 << 16;
  return c.f;
}

__device__ __forceinline__ float fast_tanh(float x) {
  float e = __builtin_amdgcn_exp2f(x * 2.8853900817779268f);
  return 1.0f - 2.0f * __builtin_amdgcn_rcpf(e + 1.0f);
}

// offset-0 global_load_lds (imm-offset shifts BOTH global and LDS addresses)
#define GLD16(g, l)                                                                    \
  __builtin_amdgcn_global_load_lds((const __attribute__((address_space(1))) void*)(g), \
                                   (__attribute__((address_space(3))) void*)(l), 16, 0, 0)

#define MFMA16(a, b, c) __builtin_amdgcn_mfma_f32_16x16x32_bf16(a, b, c, 0, 0, 0)
#define SBAR0() __builtin_amdgcn_sched_barrier(0)

// ---------------- fused prep: W1k transpose | qterm | convert keys->bf16 (deep MLP) ----------------
__global__ void prep_kernel(const float* __restrict__ keys, unsigned short* __restrict__ keysbf,
                            const float* __restrict__ W1, unsigned short* __restrict__ W1kt,
                            const float* __restrict__ query, const float* __restrict__ b1,
                            float* __restrict__ qterm) {
  __shared__ __align__(16) unsigned char smem[16896];
  const int bid = blockIdx.x;
  const int t = threadIdx.x;
  if (bid < 256) {
    float (*tt)[65] = (float(*)[65])smem;
    const int kb = (bid & 15) * 64;
    const int jb = (bid >> 4) * 64;
    const int c = t & 63;
    const int r = t >> 6;
#pragma unroll
    for (int i = 0; i < 16; ++i) {
      const int k = i * 4 + r;
      tt[k][c] = W1[(size_t)(1024 + kb + k) * 1024 + (jb + c)];
    }
    __syncthreads();
#pragma unroll
    for (int i = 0; i < 16; ++i) {
      const int j = i * 4 + r;
      W1kt[(size_t)(jb + j) * 1024 + (kb + c)] = f32_to_bf16(tt[c][j]);
    }
  } else if (bid < 512) {
    float (*part)[64] = (float(*)[64])smem;
    const int q = bid - 256;
    const int b = q >> 4;
    const int j = (q & 15) * 64 + (t & 63);
    const int kq = t >> 6;
    const float* qp = query + b * 1024 + kq * 256;
    const float* wp = W1 + (size_t)(kq * 256) * 1024 + j;
    float acc = 0.f;
#pragma unroll 8
    for (int k = 0; k < 256; ++k) acc += qp[k] * wp[(size_t)k * 1024];
    part[kq][t & 63] = acc;
    __syncthreads();
    if (t < 64) {
      const int jj = (q & 15) * 64 + t;
      qterm[b * 1024 + jj] = b1[jj] + part[0][t] + part[1][t] + part[2][t] + part[3][t];
    }
  } else {
    const size_t base = (size_t)(bid - 512) * 16384;
#pragma unroll
    for (int bt = 0; bt < 2; ++bt) {
      f32x4 v[8];
#pragma unroll
      for (int i = 0; i < 8; ++i)
        v[i] = *(const f32x4*)(keys + base + bt * 8192 + i * 1024 + t * 4);
#pragma unroll
      for (int i = 0; i < 8; ++i) {
        u32x2 p;
        p.x = pack2f(v[i].x, v[i].y);
        p.y = pack2f(v[i].z, v[i].w);
        *(u32x2*)(keysbf + base + bt * 8192 + i * 1024 + t * 4) = p;
      }
    }
  }
}

// ---------------- fused GEMM + tanh + W2-reduce (v15: 2-buffer, 2 blocks/CU, fine phases) ----------------
// 512 thr / 8 waves (2 wm x 4 wn, wave tile 128x64). Tile 256x256, BK=32, 32 k-steps.
// LDS: 2 buffers x (A 16KB + B 16KB) + Sred = 68KB -> 2 blocks/CU (16 waves) for cross-block
// stall cover. Stage S(t+1) during t into the other buffer (issue-to-drain = 1 full kt).
// Per kt, TWO fine phases: {ds_reads || 2 GLD} -> setprio 16-MFMA -> barrier.

#define V15_ITER(kt_, Pc, Ps, LAST)                                        \
  asm volatile("s_waitcnt vmcnt(0) lgkmcnt(0)" ::: "memory");              \
  __builtin_amdgcn_s_barrier();                                            \
  SBAR0();                                                                 \
  {                                                                        \
    bf16x8 af[8], bfv[4];                                                  \
    _Pragma("unroll") for (int mf = 0; mf < 4; ++mf)                       \
        af[mf] = *(const bf16x8*)((Pc) + abase + mf * 1024);               \
    _Pragma("unroll") for (int nf = 0; nf < 4; ++nf)                       \
        bfv[nf] = *(const bf16x8*)((Pc) + bbase + nf * 1024);              \
    if (!(LAST)) {                                                         \
      GLD16(gk0 + ((kt_) + 1) * 32, (Ps) + ldst);                          \
      GLD16(gw0 + ((kt_) + 1) * 32, (Ps) + 16384 + ldst);                  \
    }                                                                      \
    SBAR0();                                                               \
    __builtin_amdgcn_s_setprio(1);                                         \
    _Pragma("unroll") for (int nf = 0; nf < 4; ++nf)                       \
        _Pragma("unroll") for (int mf = 0; mf < 4; ++mf)                   \
            acc[mf][nf] = MFMA16(af[mf], bfv[nf], acc[mf][nf]);            \
    __builtin_amdgcn_s_setprio(0);                                         \
    SBAR0();                                                               \
    __builtin_amdgcn_s_barrier();                                          \
    _Pragma("unroll") for (int mf = 4; mf < 8; ++mf)                       \
        af[mf] = *(const bf16x8*)((Pc) + abase + mf * 1024);               \
    if (!(LAST)) {                                                         \
      GLD16(gk1 + ((kt_) + 1) * 32, (Ps) + 8192 + ldst);                   \
      GLD16(gw1 + ((kt_) + 1) * 32, (Ps) + 24576 + ldst);                  \
    }                                                                      \
    SBAR0();                                                               \
    __builtin_amdgcn_s_setprio(1);                                         \
    _Pragma("unroll") for (int nf = 0; nf < 4; ++nf)                       \
        _Pragma("unroll") for (int mf = 4; mf < 8; ++mf)                   \
            acc[mf][nf] = MFMA16(af[mf], bfv[nf], acc[mf][nf]);            \
    __builtin_amdgcn_s_setprio(0);                                         \
  }

#define V15_PAIR(k0, k1) \
  V15_ITER(k0, P0, P1, false) \
  V15_ITER(k1, P1, P0, false)

__global__ __launch_bounds__(512, 2) void gemm_score_v15(
    const unsigned short* __restrict__ keysbf, const unsigned short* __restrict__ W1kt,
    const float* __restrict__ qterm, const float* __restrict__ coverage,
    const float* __restrict__ W1, const float* __restrict__ W2,
    float* __restrict__ scores_part) {
  __shared__ __align__(16) unsigned char lds[69632];
  unsigned char* P0 = lds;              // A 16KB + B 16KB
  unsigned char* P1 = lds + 32768;
  float* Sred = (float*)(lds + 65536);  // 8 x 128 f32

  const int tid = threadIdx.x;
  const int bid = blockIdx.x;  // 512
  const int xcd = bid & 7;
  const int idx = bid >> 3;                // 0..63
  const int rowt = xcd * 16 + (idx >> 2);  // 0..127
  const int colgrp = idx & 3;              // 0..3
  const int row0 = rowt * 256;
  const int col0 = colgrp * 256;
  const int b = row0 >> 11;
  const int w = tid >> 6;             // 0..7
  const int wm = w >> 2, wn = w & 3;  // 2 x 4
  const int lane = tid & 63;
  const int c16 = lane & 15, q4 = lane >> 4;

  // hoisted fragment-read bases: af = P + abase + mf*1024 ; bfv = P + bbase + nf*1024
  const int swzc = (q4 ^ ((c16 >> 1) & 3)) << 4;
  const int abase = (wm * 128 + c16) * 64 + swzc;
  const int bbase = 16384 + (wn * 64 + c16) * 64 + swzc;

  // hoisted stage base pointers: u = (lane&3)^((lane>>3)&3) is i/w-invariant
  const int u = (lane & 3) ^ ((lane >> 3) & 3);
  const int r0s = w * 16 + (lane >> 2);  // rows 0..127; +128 via gk1/gw1
  const unsigned short* gk0 = keysbf + (size_t)(row0 + r0s) * 1024 + u * 8;
  const unsigned short* gk1 = keysbf + (size_t)(row0 + 128 + r0s) * 1024 + u * 8;
  const unsigned short* gw0 = W1kt + (size_t)(col0 + r0s) * 1024 + u * 8;
  const unsigned short* gw1 = W1kt + (size_t)(col0 + 128 + r0s) * 1024 + u * 8;
  const int ldst = w * 1024 + lane * 16;  // LDS dest (wave-uniform base + lane*16)

  f32x4 acc[8][4];  // [mf][nf]
  const f32x4 zz = {0.f, 0.f, 0.f, 0.f};
#pragma unroll
  for (int mf = 0; mf < 8; ++mf)
#pragma unroll
    for (int nf = 0; nf < 4; ++nf) acc[mf][nf] = zz;

  // prologue: stage S(0) -> P0 only (ITER(t) stages S(t+1))
  GLD16(gk0, P0 + ldst);
  GLD16(gw0, P0 + 16384 + ldst);
  GLD16(gk1, P0 + 8192 + ldst);
  GLD16(gw1, P0 + 24576 + ldst);

  V15_PAIR(0, 1)
  V15_PAIR(2, 3)
  V15_PAIR(4, 5)
  V15_PAIR(6, 7)
  V15_PAIR(8, 9)
  V15_PAIR(10, 11)
  V15_PAIR(12, 13)
  V15_PAIR(14, 15)
  V15_PAIR(16, 17)
  V15_PAIR(18, 19)
  V15_PAIR(20, 21)
  V15_PAIR(22, 23)
  V15_PAIR(24, 25)
  V15_PAIR(26, 27)
  V15_PAIR(28, 29)
  V15_ITER(30, P0, P1, false)
  V15_ITER(31, P1, P0, true)

  // ---- epilogue ----
  float covv[8][4];
#pragma unroll
  for (int mf = 0; mf < 8; ++mf)
#pragma unroll
    for (int r = 0; r < 4; ++r)
      covv[mf][r] = coverage[row0 + wm * 128 + mf * 16 + q4 * 4 + r];

  float p_part[8][4];
#pragma unroll
  for (int mf = 0; mf < 8; ++mf)
#pragma unroll
    for (int r = 0; r < 4; ++r) p_part[mf][r] = 0.f;

#pragma unroll
  for (int nf = 0; nf < 4; ++nf) {
    const int col = col0 + wn * 64 + nf * 16 + c16;
    const float qt = qterm[b * 1024 + col];
    const float w1c = W1[(size_t)2048 * 1024 + col];
    const float w2 = W2[col];
#pragma unroll
    for (int mf = 0; mf < 8; ++mf)
#pragma unroll
      for (int r = 0; r < 4; ++r) {
        float v = acc[mf][nf][r] + qt + covv[mf][r] * w1c;
        p_part[mf][r] += fast_tanh(v) * w2;
      }
  }

#pragma unroll
  for (int mf = 0; mf < 8; ++mf)
#pragma unroll
    for (int r = 0; r < 4; ++r) {
      float p = p_part[mf][r];
      p += __shfl_xor(p, 1);
      p += __shfl_xor(p, 2);
      p += __shfl_xor(p, 4);
      p += __shfl_xor(p, 8);
      if (c16 == 0) Sred[w * 128 + mf * 16 + q4 * 4 + r] = p;
    }
  __syncthreads();
  if (tid < 256) {
    const int wmv = tid >> 7, rl = tid & 127;
    float s = Sred[(wmv * 4 + 0) * 128 + rl] + Sred[(wmv * 4 + 1) * 128 + rl] +
              Sred[(wmv * 4 + 2) * 128 + rl] + Sred[(wmv * 4 + 3) * 128 + rl];
    scores_part[(size_t)colgrp * 32768 + row0 + tid] = s;
  }
}

// ---------------- softmax over L per batch (sums 4 colgrp partials) ----------------
__global__ void softmax_kernel(const float* __restrict__ sp, float* __restrict__ att) {
  const int b = blockIdx.x;
  const int tid = threadIdx.x;
  float* a = att + b * 2048;
  __shared__ float red[4];
  float mx = -1e30f;
  for (int l = tid; l < 2048; l += 256) {
    float v = 0.f;
#pragma unroll
    for (int g = 0; g < 4; ++g) v += sp[(size_t)g * 32768 + b * 2048 + l];
    a[l] = v;
    mx = fmaxf(mx, v);
  }
#pragma unroll
  for (int o = 1; o < 64; o <<= 1) mx = fmaxf(mx, __shfl_xor(mx, o));
  if ((tid & 63) == 0) red[tid >> 6] = mx;
  __syncthreads();
  mx = fmaxf(fmaxf(red[0], red[1]), fmaxf(red[2], red[3]));
  __syncthreads();
  float sum = 0.f;
  for (int l = tid; l < 2048; l += 256) {
    float e = __expf(a[l] - mx);
    a[l] = e;
    sum += e;
  }
#pragma unroll
  for (int o = 1; o < 64; o <<= 1) sum += __shfl_xor(sum, o);
  if ((tid & 63) == 0) red[tid >> 6] = sum;
  __syncthreads();
  sum = red[0] + red[1] + red[2] + red[3];
  const float inv = 1.0f / sum;
  for (int l = tid; l < 2048; l += 256) a[l] *= inv;
}

// ---------------- ctx_part[sl][b][j] = sum over 128 rows of att*keysbf (bf16 reads) ----------------
__global__ void ctxpre_kernel(const unsigned short* __restrict__ keysbf,
                              const float* __restrict__ att, float* __restrict__ ctx_part) {
  const int b = blockIdx.x;     // 16
  const int sl = blockIdx.y;    // 16 slices of 128 rows
  const int tid = threadIdx.x;  // 256
  const float* ab = att + b * 2048 + sl * 128;
  const unsigned short* kb = keysbf + ((size_t)b * 2048 + sl * 128) * 1024 + tid * 4;
  f32x4 acc = {0.f, 0.f, 0.f, 0.f};
#pragma unroll 4
  for (int l = 0; l < 128; ++l) {
    u32x2 v = *(const u32x2*)(kb + (size_t)l * 1024);
    const float al = ab[l];
    acc.x += bfbits_to_f32(v.x & 0xFFFFu) * al;
    acc.y += bfbits_to_f32(v.x >> 16) * al;
    acc.z += bfbits_to_f32(v.y & 0xFFFFu) * al;
    acc.w += bfbits_to_f32(v.y >> 16) * al;
  }
  *(f32x4*)(ctx_part + ((size_t)(sl * 16 + b)) * 1024 + tid * 4) = acc;
}

// ---------------- fused: ctx_pre reduce (into LDS) + context matmul ----------------
__global__ void ctx2_kernel(const float* __restrict__ ctx_part, const float* __restrict__ Wr,
                            float* __restrict__ out) {
  __shared__ float cpre[1024];
  __shared__ float part[4][64];
  const int hb = blockIdx.x;  // 8
  const int b = blockIdx.y;   // 16
  const int t = threadIdx.x;  // 256
#pragma unroll
  for (int jj = 0; jj < 4; ++jj) {
    const int j = jj * 256 + t;
    float s = 0.f;
#pragma unroll
    for (int sl = 0; sl < 16; ++sl) s += ctx_part[((size_t)(sl * 16 + b)) * 1024 + j];
    cpre[j] = s;
  }
  __syncthreads();
  const int h = hb * 64 + (t & 63);
  const int jq = t >> 6;
  const float* wp = Wr + (size_t)(jq * 256) * 512 + h;
  float acc = 0.f;
#pragma unroll 8
  for (int k = 0; k < 256; ++k) acc += cpre[jq * 256 + k] * wp[(size_t)k * 512];
  part[jq][t & 63] = acc;
  __syncthreads();
  if (t < 64)
    out[b * 512 + hb * 64 + t] = part[0][t] + part[1][t] + part[2][t] + part[3][t];
}

extern "C" void kernel_launch(void* const* d_in, const int* in_sizes, int n_in, void* d_out,
                              int out_size, void* d_ws, size_t ws_size, hipStream_t stream) {
  const float* query = (const float*)d_in[0];     // (16,1,1024)
  const float* keys = (const float*)d_in[1];      // (16,2048,1024)
  const float* coverage = (const float*)d_in[2];  // (16,2048,1)
  const float* W1 = (const float*)d_in[3];        // (2049,1024)
  const float* b1 = (const float*)d_in[4];        // (1024,)
  const float* W2 = (const float*)d_in[5];        // (1024,1)
  const float* Wr = (const float*)d_in[6];        // (1024,512)
  float* out = (float*)d_out;
  char* ws = (char*)d_ws;

  float* scores_part = (float*)ws;          // 4*32768 f32 = 512KB @ 0
  float* ctx_part = (float*)ws;             // 1MB, aliases scores_part (dead after softmax)
  float* qterm = (float*)(ws + 1114112);    // 16384 f32
  unsigned short* W1kt = (unsigned short*)(ws + 1179648);    // 1M bf16 (2MB)
  unsigned short* keysbf = (unsigned short*)(ws + 3276800);  // 32M bf16 (64MB)

  float* context_out = out;     // 16*512
  float* att_out = out + 8192;  // 16*2048

  prep_kernel<<<dim3(2560), dim3(256), 0, stream>>>(keys, keysbf, W1, W1kt, query, b1, qterm);
  gemm_score_v15<<<dim3(512), dim3(512), 0, stream>>>(keysbf, W1kt, qterm, coverage, W1, W2,
                                                      scores_part);
  softmax_kernel<<<dim3(16), dim3(256), 0, stream>>>(scores_part, att_out);
  ctxpre_kernel<<<dim3(16, 16), dim3(256), 0, stream>>>(keysbf, att_out, ctx_part);
  ctx2_kernel<<<dim3(8, 16), dim3(256), 0, stream>>>(ctx_part, Wr, context_out);
}

// Round 19
// 131.413 us; speedup vs baseline: 1.0913x; 1.0913x over previous
//
#include <hip/hip_runtime.h>
#include <hip/hip_bf16.h>
#include <stdint.h>

typedef short bf16x8 __attribute__((ext_vector_type(8)));
typedef float f32x4 __attribute__((ext_vector_type(4)));
typedef unsigned int u32x2 __attribute__((ext_vector_type(2)));

__device__ __forceinline__ uint32_t pack2f(float lo, float hi) {
  union { __hip_bfloat162 h; uint32_t u; } c;
  c.h.x = __float2bfloat16(lo);
  c.h.y = __float2bfloat16(hi);
  return c.u;
}

__device__ __forceinline__ unsigned short f32_to_bf16(float f) {
  union { __hip_bfloat16 h; unsigned short u; } c;
  c.h = __float2bfloat16(f);
  return c.u;
}

__device__ __forceinline__ float bfbits_to_f32(uint32_t hi16) {
  union { uint32_t u; float f; } c;
  c.u = hi16 << 16;
  return c.f;
}

__device__ __forceinline__ float fast_tanh(float x) {
  float e = __builtin_amdgcn_exp2f(x * 2.8853900817779268f);
  return 1.0f - 2.0f * __builtin_amdgcn_rcpf(e + 1.0f);
}

// offset-0 global_load_lds (imm-offset shifts BOTH global and LDS addresses)
#define GLD16(g, l)                                                                    \
  __builtin_amdgcn_global_load_lds((const __attribute__((address_space(1))) void*)(g), \
                                   (__attribute__((address_space(3))) void*)(l), 16, 0, 0)

#define MFMA16(a, b, c) __builtin_amdgcn_mfma_f32_16x16x32_bf16(a, b, c, 0, 0, 0)
#define SBAR0() __builtin_amdgcn_sched_barrier(0)

// ---------------- fused prep: W1k transpose | qterm | convert keys->bf16 (deep MLP) ----------------
__global__ void prep_kernel(const float* __restrict__ keys, unsigned short* __restrict__ keysbf,
                            const float* __restrict__ W1, unsigned short* __restrict__ W1kt,
                            const float* __restrict__ query, const float* __restrict__ b1,
                            float* __restrict__ qterm) {
  __shared__ __align__(16) unsigned char smem[16896];
  const int bid = blockIdx.x;
  const int t = threadIdx.x;
  if (bid < 256) {
    float (*tt)[65] = (float(*)[65])smem;
    const int kb = (bid & 15) * 64;
    const int jb = (bid >> 4) * 64;
    const int c = t & 63;
    const int r = t >> 6;
#pragma unroll
    for (int i = 0; i < 16; ++i) {
      const int k = i * 4 + r;
      tt[k][c] = W1[(size_t)(1024 + kb + k) * 1024 + (jb + c)];
    }
    __syncthreads();
#pragma unroll
    for (int i = 0; i < 16; ++i) {
      const int j = i * 4 + r;
      W1kt[(size_t)(jb + j) * 1024 + (kb + c)] = f32_to_bf16(tt[c][j]);
    }
  } else if (bid < 512) {
    float (*part)[64] = (float(*)[64])smem;
    const int q = bid - 256;
    const int b = q >> 4;
    const int j = (q & 15) * 64 + (t & 63);
    const int kq = t >> 6;
    const float* qp = query + b * 1024 + kq * 256;
    const float* wp = W1 + (size_t)(kq * 256) * 1024 + j;
    float acc = 0.f;
#pragma unroll 8
    for (int k = 0; k < 256; ++k) acc += qp[k] * wp[(size_t)k * 1024];
    part[kq][t & 63] = acc;
    __syncthreads();
    if (t < 64) {
      const int jj = (q & 15) * 64 + t;
      qterm[b * 1024 + jj] = b1[jj] + part[0][t] + part[1][t] + part[2][t] + part[3][t];
    }
  } else {
    const size_t base = (size_t)(bid - 512) * 16384;
#pragma unroll
    for (int bt = 0; bt < 2; ++bt) {
      f32x4 v[8];
#pragma unroll
      for (int i = 0; i < 8; ++i)
        v[i] = *(const f32x4*)(keys + base + bt * 8192 + i * 1024 + t * 4);
#pragma unroll
      for (int i = 0; i < 8; ++i) {
        u32x2 p;
        p.x = pack2f(v[i].x, v[i].y);
        p.y = pack2f(v[i].z, v[i].w);
        *(u32x2*)(keysbf + base + bt * 8192 + i * 1024 + t * 4) = p;
      }
    }
  }
}

// ---------------- fused GEMM + tanh + W2-reduce (v16b: BK=64 superbuffers, 16 barriers) ----------------
// 512 thr / 8 waves (2 wm x 4 wn, wave tile 128x64). Tile 256x256, BK=64, 16 K-tiles.
// LDS: 2 x (A 32KB + B 32KB) = 128KB + Sred 4KB (1 block/CU). One drain+barrier per K-tile.
// Swizzle: stage puts global unit g of row r in LDS slot g^(r&7); read must use
// slot (kk*4+q4)^(c16&7) -> byte = swzc ^ (kk*64). XOR, NOT ADD (round-18 NaN was the add-carry).

#define V16_STAGE(kt_, P)                                            \
  GLD16(gkA + (kt_) * 64 + 0 * 65536, (P) + 0 * 8192 + t16);         \
  GLD16(gwB + (kt_) * 64 + 0 * 65536, (P) + 32768 + 0 * 8192 + t16); \
  GLD16(gkA + (kt_) * 64 + 1 * 65536, (P) + 1 * 8192 + t16);         \
  GLD16(gwB + (kt_) * 64 + 1 * 65536, (P) + 32768 + 1 * 8192 + t16); \
  GLD16(gkA + (kt_) * 64 + 2 * 65536, (P) + 2 * 8192 + t16);         \
  GLD16(gwB + (kt_) * 64 + 2 * 65536, (P) + 32768 + 2 * 8192 + t16); \
  GLD16(gkA + (kt_) * 64 + 3 * 65536, (P) + 3 * 8192 + t16);         \
  GLD16(gwB + (kt_) * 64 + 3 * 65536, (P) + 32768 + 3 * 8192 + t16);

#define V16_COMPUTE(P)                                                           \
  _Pragma("unroll") for (int kk = 0; kk < 2; ++kk) {                             \
    bf16x8 af[8], bfv[4];                                                        \
    _Pragma("unroll") for (int mf = 0; mf < 8; ++mf)                             \
        af[mf] = *(const bf16x8*)((P) + ((abase + mf * 2048) ^ (kk * 64)));      \
    _Pragma("unroll") for (int nf = 0; nf < 4; ++nf)                             \
        bfv[nf] = *(const bf16x8*)((P) + ((bbase + nf * 2048) ^ (kk * 64)));     \
    __builtin_amdgcn_s_setprio(1);                                               \
    _Pragma("unroll") for (int nf = 0; nf < 4; ++nf)                             \
        _Pragma("unroll") for (int mf = 0; mf < 8; ++mf) acc[mf][nf] =           \
            MFMA16(af[mf], bfv[nf], acc[mf][nf]);                                \
    __builtin_amdgcn_s_setprio(0);                                               \
  }

#define V16_ITER(t_, Pc, Ps, LAST)                            \
  asm volatile("s_waitcnt vmcnt(0) lgkmcnt(0)" ::: "memory"); \
  __builtin_amdgcn_s_barrier();                               \
  SBAR0();                                                    \
  if (!(LAST)) { V16_STAGE((t_) + 1, Ps); }                   \
  SBAR0();                                                    \
  V16_COMPUTE(Pc);

#define V16_PAIR(t0, t1)      \
  V16_ITER(t0, P0, P1, false) \
  V16_ITER(t1, P1, P0, (t1) == 15)

__global__ __launch_bounds__(512, 2) void gemm_score_v16(
    const unsigned short* __restrict__ keysbf, const unsigned short* __restrict__ W1kt,
    const float* __restrict__ qterm, const float* __restrict__ coverage,
    const float* __restrict__ W1, const float* __restrict__ W2,
    float* __restrict__ scores_part) {
  __shared__ __align__(16) unsigned char lds[135168];
  unsigned char* P0 = lds;               // A 32KB + B 32KB
  unsigned char* P1 = lds + 65536;
  float* Sred = (float*)(lds + 131072);  // 8 x 128 f32

  const int tid = threadIdx.x;
  const int bid = blockIdx.x;  // 512
  const int xcd = bid & 7;
  const int idx = bid >> 3;                // 0..63
  const int rowt = xcd * 16 + (idx >> 2);  // 0..127
  const int colgrp = idx & 3;              // 0..3
  const int row0 = rowt * 256;
  const int col0 = colgrp * 256;
  const int b = row0 >> 11;
  const int w = tid >> 6;             // 0..7
  const int wm = w >> 2, wn = w & 3;  // 2 x 4
  const int lane = tid & 63;
  const int c16 = lane & 15, q4 = lane >> 4;

  // fragment-read bases; per-kk byte-in-row advances by XOR (see header comment)
  const int swzc = (q4 ^ (c16 & 7)) << 4;
  const int abase = (wm * 128 + c16) * 128 + swzc;
  const int bbase = 32768 + (wn * 64 + c16) * 128 + swzc;

  // stage base pointers: row r = (tid>>3) + i*64, unit u = (tid&7) ^ (r&7)  (i-invariant)
  const int sr = tid >> 3;
  const int su = (tid & 7) ^ (sr & 7);
  const unsigned short* gkA = keysbf + (size_t)(row0 + sr) * 1024 + su * 8;
  const unsigned short* gwB = W1kt + (size_t)(col0 + sr) * 1024 + su * 8;
  const int t16 = tid * 16;  // linear LDS dest

  f32x4 acc[8][4];  // [mf][nf]
  const f32x4 zz = {0.f, 0.f, 0.f, 0.f};
#pragma unroll
  for (int mf = 0; mf < 8; ++mf)
#pragma unroll
    for (int nf = 0; nf < 4; ++nf) acc[mf][nf] = zz;

  // prologue: stage S(0)->P0
  V16_STAGE(0, P0);

  V16_PAIR(0, 1)
  V16_PAIR(2, 3)
  V16_PAIR(4, 5)
  V16_PAIR(6, 7)
  V16_PAIR(8, 9)
  V16_PAIR(10, 11)
  V16_PAIR(12, 13)
  V16_PAIR(14, 15)

  // ---- epilogue ----
  float covv[8][4];
#pragma unroll
  for (int mf = 0; mf < 8; ++mf)
#pragma unroll
    for (int r = 0; r < 4; ++r)
      covv[mf][r] = coverage[row0 + wm * 128 + mf * 16 + q4 * 4 + r];

  float p_part[8][4];
#pragma unroll
  for (int mf = 0; mf < 8; ++mf)
#pragma unroll
    for (int r = 0; r < 4; ++r) p_part[mf][r] = 0.f;

#pragma unroll
  for (int nf = 0; nf < 4; ++nf) {
    const int col = col0 + wn * 64 + nf * 16 + c16;
    const float qt = qterm[b * 1024 + col];
    const float w1c = W1[(size_t)2048 * 1024 + col];
    const float w2 = W2[col];
#pragma unroll
    for (int mf = 0; mf < 8; ++mf)
#pragma unroll
      for (int r = 0; r < 4; ++r) {
        float v = acc[mf][nf][r] + qt + covv[mf][r] * w1c;
        p_part[mf][r] += fast_tanh(v) * w2;
      }
  }

#pragma unroll
  for (int mf = 0; mf < 8; ++mf)
#pragma unroll
    for (int r = 0; r < 4; ++r) {
      float p = p_part[mf][r];
      p += __shfl_xor(p, 1);
      p += __shfl_xor(p, 2);
      p += __shfl_xor(p, 4);
      p += __shfl_xor(p, 8);
      if (c16 == 0) Sred[w * 128 + mf * 16 + q4 * 4 + r] = p;
    }
  __syncthreads();
  if (tid < 256) {
    const int wmv = tid >> 7, rl = tid & 127;
    float s = Sred[(wmv * 4 + 0) * 128 + rl] + Sred[(wmv * 4 + 1) * 128 + rl] +
              Sred[(wmv * 4 + 2) * 128 + rl] + Sred[(wmv * 4 + 3) * 128 + rl];
    scores_part[(size_t)colgrp * 32768 + row0 + tid] = s;
  }
}

// ---------------- fused softmax + ctx_part ----------------
__global__ void ctxpre_fused(const unsigned short* __restrict__ keysbf,
                             const float* __restrict__ sp, float* __restrict__ att,
                             float* __restrict__ ctx_part) {
  __shared__ float sc[2048];
  __shared__ float red[4];
  __shared__ float att_s[128];
  const int b = blockIdx.x;     // 16
  const int sl = blockIdx.y;    // 16 slices of 128 rows
  const int tid = threadIdx.x;  // 256
  float mx = -1e30f;
  for (int l = tid; l < 2048; l += 256) {
    float v = 0.f;
#pragma unroll
    for (int g = 0; g < 4; ++g) v += sp[(size_t)g * 32768 + b * 2048 + l];
    sc[l] = v;
    mx = fmaxf(mx, v);
  }
#pragma unroll
  for (int o = 1; o < 64; o <<= 1) mx = fmaxf(mx, __shfl_xor(mx, o));
  if ((tid & 63) == 0) red[tid >> 6] = mx;
  __syncthreads();
  mx = fmaxf(fmaxf(red[0], red[1]), fmaxf(red[2], red[3]));
  __syncthreads();
  float sum = 0.f;
  for (int l = tid; l < 2048; l += 256) sum += __expf(sc[l] - mx);
#pragma unroll
  for (int o = 1; o < 64; o <<= 1) sum += __shfl_xor(sum, o);
  if ((tid & 63) == 0) red[tid >> 6] = sum;
  __syncthreads();
  const float inv = 1.0f / (red[0] + red[1] + red[2] + red[3]);
  if (tid < 128) {
    const float a = __expf(sc[sl * 128 + tid] - mx) * inv;
    att_s[tid] = a;
    att[b * 2048 + sl * 128 + tid] = a;
  }
  __syncthreads();

  const unsigned short* kb = keysbf + ((size_t)b * 2048 + sl * 128) * 1024 + tid * 4;
  f32x4 acc = {0.f, 0.f, 0.f, 0.f};
#pragma unroll 4
  for (int l = 0; l < 128; ++l) {
    u32x2 v = *(const u32x2*)(kb + (size_t)l * 1024);
    const float al = att_s[l];
    acc.x += bfbits_to_f32(v.x & 0xFFFFu) * al;
    acc.y += bfbits_to_f32(v.x >> 16) * al;
    acc.z += bfbits_to_f32(v.y & 0xFFFFu) * al;
    acc.w += bfbits_to_f32(v.y >> 16) * al;
  }
  *(f32x4*)(ctx_part + ((size_t)(sl * 16 + b)) * 1024 + tid * 4) = acc;
}

// ---------------- fused: ctx_pre reduce (into LDS) + context matmul ----------------
__global__ void ctx2_kernel(const float* __restrict__ ctx_part, const float* __restrict__ Wr,
                            float* __restrict__ out) {
  __shared__ float cpre[1024];
  __shared__ float part[4][64];
  const int hb = blockIdx.x;  // 8
  const int b = blockIdx.y;   // 16
  const int t = threadIdx.x;  // 256
#pragma unroll
  for (int jj = 0; jj < 4; ++jj) {
    const int j = jj * 256 + t;
    float s = 0.f;
#pragma unroll
    for (int sl = 0; sl < 16; ++sl) s += ctx_part[((size_t)(sl * 16 + b)) * 1024 + j];
    cpre[j] = s;
  }
  __syncthreads();
  const int h = hb * 64 + (t & 63);
  const int jq = t >> 6;
  const float* wp = Wr + (size_t)(jq * 256) * 512 + h;
  float acc = 0.f;
#pragma unroll 8
  for (int k = 0; k < 256; ++k) acc += cpre[jq * 256 + k] * wp[(size_t)k * 512];
  part[jq][t & 63] = acc;
  __syncthreads();
  if (t < 64)
    out[b * 512 + hb * 64 + t] = part[0][t] + part[1][t] + part[2][t] + part[3][t];
}

extern "C" void kernel_launch(void* const* d_in, const int* in_sizes, int n_in, void* d_out,
                              int out_size, void* d_ws, size_t ws_size, hipStream_t stream) {
  const float* query = (const float*)d_in[0];     // (16,1,1024)
  const float* keys = (const float*)d_in[1];      // (16,2048,1024)
  const float* coverage = (const float*)d_in[2];  // (16,2048,1)
  const float* W1 = (const float*)d_in[3];        // (2049,1024)
  const float* b1 = (const float*)d_in[4];        // (1024,)
  const float* W2 = (const float*)d_in[5];        // (1024,1)
  const float* Wr = (const float*)d_in[6];        // (1024,512)
  float* out = (float*)d_out;
  char* ws = (char*)d_ws;

  float* scores_part = (float*)ws;          // 4*32768 f32 = 512KB @ 0
  float* ctx_part = (float*)(ws + 524288);  // 16*16*1024 f32 = 1MB
  float* qterm = (float*)(ws + 1638400);    // 16384 f32
  unsigned short* W1kt = (unsigned short*)(ws + 1703936);    // 1M bf16 (2MB)
  unsigned short* keysbf = (unsigned short*)(ws + 3801088);  // 32M bf16 (64MB)

  float* context_out = out;     // 16*512
  float* att_out = out + 8192;  // 16*2048

  prep_kernel<<<dim3(2560), dim3(256), 0, stream>>>(keys, keysbf, W1, W1kt, query, b1, qterm);
  gemm_score_v16<<<dim3(512), dim3(512), 0, stream>>>(keysbf, W1kt, qterm, coverage, W1, W2,
                                                      scores_part);
  ctxpre_fused<<<dim3(16, 16), dim3(256), 0, stream>>>(keysbf, scores_part, att_out, ctx_part);
  ctx2_kernel<<<dim3(8, 16), dim3(256), 0, stream>>>(ctx_part, Wr, context_out);
}

// Round 20
// 131.366 us; speedup vs baseline: 1.0917x; 1.0004x over previous
//
#include <hip/hip_runtime.h>
#include <hip/hip_bf16.h>
#include <stdint.h>

typedef short bf16x8 __attribute__((ext_vector_type(8)));
typedef float f32x4 __attribute__((ext_vector_type(4)));
typedef unsigned int u32x2 __attribute__((ext_vector_type(2)));

__device__ __forceinline__ uint32_t pack2f(float lo, float hi) {
  union { __hip_bfloat162 h; uint32_t u; } c;
  c.h.x = __float2bfloat16(lo);
  c.h.y = __float2bfloat16(hi);
  return c.u;
}

__device__ __forceinline__ unsigned short f32_to_bf16(float f) {
  union { __hip_bfloat16 h; unsigned short u; } c;
  c.h = __float2bfloat16(f);
  return c.u;
}

__device__ __forceinline__ float bfbits_to_f32(uint32_t hi16) {
  union { uint32_t u; float f; } c;
  c.u = hi16 << 16;
  return c.f;
}

__device__ __forceinline__ float fast_tanh(float x) {
  float e = __builtin_amdgcn_exp2f(x * 2.8853900817779268f);
  return 1.0f - 2.0f * __builtin_amdgcn_rcpf(e + 1.0f);
}

// offset-0 global_load_lds (imm-offset shifts BOTH global and LDS addresses)
#define GLD16(g, l)                                                                    \
  __builtin_amdgcn_global_load_lds((const __attribute__((address_space(1))) void*)(g), \
                                   (__attribute__((address_space(3))) void*)(l), 16, 0, 0)

#define MFMA16(a, b, c) __builtin_amdgcn_mfma_f32_16x16x32_bf16(a, b, c, 0, 0, 0)
#define SBAR0() __builtin_amdgcn_sched_barrier(0)

// ---------------- fused prep: W1k transpose | qterm | convert keys->bf16 ----------------
// Convert: 8 named-register f32x4 loads, then sched_barrier(0), then pack+store.
// The barrier pins all 8 loads in flight (compiler had serialized the array version
// down to VGPR=32 / 1-2 outstanding -> 1.8 TB/s).
__global__ void prep_kernel(const float* __restrict__ keys, unsigned short* __restrict__ keysbf,
                            const float* __restrict__ W1, unsigned short* __restrict__ W1kt,
                            const float* __restrict__ query, const float* __restrict__ b1,
                            float* __restrict__ qterm) {
  __shared__ __align__(16) unsigned char smem[16896];
  const int bid = blockIdx.x;
  const int t = threadIdx.x;
  if (bid < 256) {
    float (*tt)[65] = (float(*)[65])smem;
    const int kb = (bid & 15) * 64;
    const int jb = (bid >> 4) * 64;
    const int c = t & 63;
    const int r = t >> 6;
#pragma unroll
    for (int i = 0; i < 16; ++i) {
      const int k = i * 4 + r;
      tt[k][c] = W1[(size_t)(1024 + kb + k) * 1024 + (jb + c)];
    }
    __syncthreads();
#pragma unroll
    for (int i = 0; i < 16; ++i) {
      const int j = i * 4 + r;
      W1kt[(size_t)(jb + j) * 1024 + (kb + c)] = f32_to_bf16(tt[c][j]);
    }
  } else if (bid < 512) {
    float (*part)[64] = (float(*)[64])smem;
    const int q = bid - 256;
    const int b = q >> 4;
    const int j = (q & 15) * 64 + (t & 63);
    const int kq = t >> 6;
    const float* qp = query + b * 1024 + kq * 256;
    const float* wp = W1 + (size_t)(kq * 256) * 1024 + j;
    float acc = 0.f;
#pragma unroll 8
    for (int k = 0; k < 256; ++k) acc += qp[k] * wp[(size_t)k * 1024];
    part[kq][t & 63] = acc;
    __syncthreads();
    if (t < 64) {
      const int jj = (q & 15) * 64 + t;
      qterm[b * 1024 + jj] = b1[jj] + part[0][t] + part[1][t] + part[2][t] + part[3][t];
    }
  } else {
    const size_t base = (size_t)(bid - 512) * 16384;
#pragma unroll
    for (int bt = 0; bt < 2; ++bt) {
      const float* src = keys + base + bt * 8192 + t * 4;
      f32x4 v0 = *(const f32x4*)(src + 0 * 1024);
      f32x4 v1 = *(const f32x4*)(src + 1 * 1024);
      f32x4 v2 = *(const f32x4*)(src + 2 * 1024);
      f32x4 v3 = *(const f32x4*)(src + 3 * 1024);
      f32x4 v4 = *(const f32x4*)(src + 4 * 1024);
      f32x4 v5 = *(const f32x4*)(src + 5 * 1024);
      f32x4 v6 = *(const f32x4*)(src + 6 * 1024);
      f32x4 v7 = *(const f32x4*)(src + 7 * 1024);
      SBAR0();  // all 8 loads issued before any pack/store (forces 8-deep MLP)
      unsigned short* dst = keysbf + base + bt * 8192 + t * 4;
      u32x2 p;
      p.x = pack2f(v0.x, v0.y); p.y = pack2f(v0.z, v0.w); *(u32x2*)(dst + 0 * 1024) = p;
      p.x = pack2f(v1.x, v1.y); p.y = pack2f(v1.z, v1.w); *(u32x2*)(dst + 1 * 1024) = p;
      p.x = pack2f(v2.x, v2.y); p.y = pack2f(v2.z, v2.w); *(u32x2*)(dst + 2 * 1024) = p;
      p.x = pack2f(v3.x, v3.y); p.y = pack2f(v3.z, v3.w); *(u32x2*)(dst + 3 * 1024) = p;
      p.x = pack2f(v4.x, v4.y); p.y = pack2f(v4.z, v4.w); *(u32x2*)(dst + 4 * 1024) = p;
      p.x = pack2f(v5.x, v5.y); p.y = pack2f(v5.z, v5.w); *(u32x2*)(dst + 5 * 1024) = p;
      p.x = pack2f(v6.x, v6.y); p.y = pack2f(v6.z, v6.w); *(u32x2*)(dst + 6 * 1024) = p;
      p.x = pack2f(v7.x, v7.y); p.y = pack2f(v7.z, v7.w); *(u32x2*)(dst + 7 * 1024) = p;
    }
  }
}

// ---------------- fused GEMM + tanh + W2-reduce (v16b: BK=64 superbuffers, 16 barriers) ----------------
// 512 thr / 8 waves (2 wm x 4 wn, wave tile 128x64). Tile 256x256, BK=64, 16 K-tiles.
// LDS: 2 x (A 32KB + B 32KB) = 128KB + Sred 4KB (1 block/CU). One drain+barrier per K-tile.
// Swizzle: stage puts global unit g of row r in LDS slot g^(r&7); read uses
// byte = swzc ^ (kk*64) -- XOR, NOT ADD (round-18 NaN was the add-carry).

#define V16_STAGE(kt_, P)                                            \
  GLD16(gkA + (kt_) * 64 + 0 * 65536, (P) + 0 * 8192 + t16);         \
  GLD16(gwB + (kt_) * 64 + 0 * 65536, (P) + 32768 + 0 * 8192 + t16); \
  GLD16(gkA + (kt_) * 64 + 1 * 65536, (P) + 1 * 8192 + t16);         \
  GLD16(gwB + (kt_) * 64 + 1 * 65536, (P) + 32768 + 1 * 8192 + t16); \
  GLD16(gkA + (kt_) * 64 + 2 * 65536, (P) + 2 * 8192 + t16);         \
  GLD16(gwB + (kt_) * 64 + 2 * 65536, (P) + 32768 + 2 * 8192 + t16); \
  GLD16(gkA + (kt_) * 64 + 3 * 65536, (P) + 3 * 8192 + t16);         \
  GLD16(gwB + (kt_) * 64 + 3 * 65536, (P) + 32768 + 3 * 8192 + t16);

#define V16_COMPUTE(P)                                                           \
  _Pragma("unroll") for (int kk = 0; kk < 2; ++kk) {                             \
    bf16x8 af[8], bfv[4];                                                        \
    _Pragma("unroll") for (int mf = 0; mf < 8; ++mf)                             \
        af[mf] = *(const bf16x8*)((P) + ((abase + mf * 2048) ^ (kk * 64)));      \
    _Pragma("unroll") for (int nf = 0; nf < 4; ++nf)                             \
        bfv[nf] = *(const bf16x8*)((P) + ((bbase + nf * 2048) ^ (kk * 64)));     \
    __builtin_amdgcn_s_setprio(1);                                               \
    _Pragma("unroll") for (int nf = 0; nf < 4; ++nf)                             \
        _Pragma("unroll") for (int mf = 0; mf < 8; ++mf) acc[mf][nf] =           \
            MFMA16(af[mf], bfv[nf], acc[mf][nf]);                                \
    __builtin_amdgcn_s_setprio(0);                                               \
  }

#define V16_ITER(t_, Pc, Ps, LAST)                            \
  asm volatile("s_waitcnt vmcnt(0) lgkmcnt(0)" ::: "memory"); \
  __builtin_amdgcn_s_barrier();                               \
  SBAR0();                                                    \
  if (!(LAST)) { V16_STAGE((t_) + 1, Ps); }                   \
  SBAR0();                                                    \
  V16_COMPUTE(Pc);

#define V16_PAIR(t0, t1)      \
  V16_ITER(t0, P0, P1, false) \
  V16_ITER(t1, P1, P0, (t1) == 15)

__global__ __launch_bounds__(512, 2) void gemm_score_v16(
    const unsigned short* __restrict__ keysbf, const unsigned short* __restrict__ W1kt,
    const float* __restrict__ qterm, const float* __restrict__ coverage,
    const float* __restrict__ W1, const float* __restrict__ W2,
    float* __restrict__ scores_part) {
  __shared__ __align__(16) unsigned char lds[135168];
  unsigned char* P0 = lds;               // A 32KB + B 32KB
  unsigned char* P1 = lds + 65536;
  float* Sred = (float*)(lds + 131072);  // 8 x 128 f32

  const int tid = threadIdx.x;
  const int bid = blockIdx.x;  // 512
  const int xcd = bid & 7;
  const int idx = bid >> 3;                // 0..63
  const int rowt = xcd * 16 + (idx >> 2);  // 0..127
  const int colgrp = idx & 3;              // 0..3
  const int row0 = rowt * 256;
  const int col0 = colgrp * 256;
  const int b = row0 >> 11;
  const int w = tid >> 6;             // 0..7
  const int wm = w >> 2, wn = w & 3;  // 2 x 4
  const int lane = tid & 63;
  const int c16 = lane & 15, q4 = lane >> 4;

  const int swzc = (q4 ^ (c16 & 7)) << 4;
  const int abase = (wm * 128 + c16) * 128 + swzc;
  const int bbase = 32768 + (wn * 64 + c16) * 128 + swzc;

  const int sr = tid >> 3;
  const int su = (tid & 7) ^ (sr & 7);
  const unsigned short* gkA = keysbf + (size_t)(row0 + sr) * 1024 + su * 8;
  const unsigned short* gwB = W1kt + (size_t)(col0 + sr) * 1024 + su * 8;
  const int t16 = tid * 16;  // linear LDS dest

  f32x4 acc[8][4];  // [mf][nf]
  const f32x4 zz = {0.f, 0.f, 0.f, 0.f};
#pragma unroll
  for (int mf = 0; mf < 8; ++mf)
#pragma unroll
    for (int nf = 0; nf < 4; ++nf) acc[mf][nf] = zz;

  V16_STAGE(0, P0);

  V16_PAIR(0, 1)
  V16_PAIR(2, 3)
  V16_PAIR(4, 5)
  V16_PAIR(6, 7)
  V16_PAIR(8, 9)
  V16_PAIR(10, 11)
  V16_PAIR(12, 13)
  V16_PAIR(14, 15)

  // ---- epilogue ----
  float covv[8][4];
#pragma unroll
  for (int mf = 0; mf < 8; ++mf)
#pragma unroll
    for (int r = 0; r < 4; ++r)
      covv[mf][r] = coverage[row0 + wm * 128 + mf * 16 + q4 * 4 + r];

  float p_part[8][4];
#pragma unroll
  for (int mf = 0; mf < 8; ++mf)
#pragma unroll
    for (int r = 0; r < 4; ++r) p_part[mf][r] = 0.f;

#pragma unroll
  for (int nf = 0; nf < 4; ++nf) {
    const int col = col0 + wn * 64 + nf * 16 + c16;
    const float qt = qterm[b * 1024 + col];
    const float w1c = W1[(size_t)2048 * 1024 + col];
    const float w2 = W2[col];
#pragma unroll
    for (int mf = 0; mf < 8; ++mf)
#pragma unroll
      for (int r = 0; r < 4; ++r) {
        float v = acc[mf][nf][r] + qt + covv[mf][r] * w1c;
        p_part[mf][r] += fast_tanh(v) * w2;
      }
  }

#pragma unroll
  for (int mf = 0; mf < 8; ++mf)
#pragma unroll
    for (int r = 0; r < 4; ++r) {
      float p = p_part[mf][r];
      p += __shfl_xor(p, 1);
      p += __shfl_xor(p, 2);
      p += __shfl_xor(p, 4);
      p += __shfl_xor(p, 8);
      if (c16 == 0) Sred[w * 128 + mf * 16 + q4 * 4 + r] = p;
    }
  __syncthreads();
  if (tid < 256) {
    const int wmv = tid >> 7, rl = tid & 127;
    float s = Sred[(wmv * 4 + 0) * 128 + rl] + Sred[(wmv * 4 + 1) * 128 + rl] +
              Sred[(wmv * 4 + 2) * 128 + rl] + Sred[(wmv * 4 + 3) * 128 + rl];
    scores_part[(size_t)colgrp * 32768 + row0 + tid] = s;
  }
}

// ---------------- fused softmax + ctx_part ----------------
__global__ void ctxpre_fused(const unsigned short* __restrict__ keysbf,
                             const float* __restrict__ sp, float* __restrict__ att,
                             float* __restrict__ ctx_part) {
  __shared__ float sc[2048];
  __shared__ float red[4];
  __shared__ float att_s[128];
  const int b = blockIdx.x;     // 16
  const int sl = blockIdx.y;    // 16 slices of 128 rows
  const int tid = threadIdx.x;  // 256
  float mx = -1e30f;
  for (int l = tid; l < 2048; l += 256) {
    float v = 0.f;
#pragma unroll
    for (int g = 0; g < 4; ++g) v += sp[(size_t)g * 32768 + b * 2048 + l];
    sc[l] = v;
    mx = fmaxf(mx, v);
  }
#pragma unroll
  for (int o = 1; o < 64; o <<= 1) mx = fmaxf(mx, __shfl_xor(mx, o));
  if ((tid & 63) == 0) red[tid >> 6] = mx;
  __syncthreads();
  mx = fmaxf(fmaxf(red[0], red[1]), fmaxf(red[2], red[3]));
  __syncthreads();
  float sum = 0.f;
  for (int l = tid; l < 2048; l += 256) sum += __expf(sc[l] - mx);
#pragma unroll
  for (int o = 1; o < 64; o <<= 1) sum += __shfl_xor(sum, o);
  if ((tid & 63) == 0) red[tid >> 6] = sum;
  __syncthreads();
  const float inv = 1.0f / (red[0] + red[1] + red[2] + red[3]);
  if (tid < 128) {
    const float a = __expf(sc[sl * 128 + tid] - mx) * inv;
    att_s[tid] = a;
    att[b * 2048 + sl * 128 + tid] = a;
  }
  __syncthreads();

  const unsigned short* kb = keysbf + ((size_t)b * 2048 + sl * 128) * 1024 + tid * 4;
  f32x4 acc = {0.f, 0.f, 0.f, 0.f};
#pragma unroll 4
  for (int l = 0; l < 128; ++l) {
    u32x2 v = *(const u32x2*)(kb + (size_t)l * 1024);
    const float al = att_s[l];
    acc.x += bfbits_to_f32(v.x & 0xFFFFu) * al;
    acc.y += bfbits_to_f32(v.x >> 16) * al;
    acc.z += bfbits_to_f32(v.y & 0xFFFFu) * al;
    acc.w += bfbits_to_f32(v.y >> 16) * al;
  }
  *(f32x4*)(ctx_part + ((size_t)(sl * 16 + b)) * 1024 + tid * 4) = acc;
}

// ---------------- fused: ctx_pre reduce (into LDS) + context matmul ----------------
__global__ void ctx2_kernel(const float* __restrict__ ctx_part, const float* __restrict__ Wr,
                            float* __restrict__ out) {
  __shared__ float cpre[1024];
  __shared__ float part[4][64];
  const int hb = blockIdx.x;  // 8
  const int b = blockIdx.y;   // 16
  const int t = threadIdx.x;  // 256
#pragma unroll
  for (int jj = 0; jj < 4; ++jj) {
    const int j = jj * 256 + t;
    float s = 0.f;
#pragma unroll
    for (int sl = 0; sl < 16; ++sl) s += ctx_part[((size_t)(sl * 16 + b)) * 1024 + j];
    cpre[j] = s;
  }
  __syncthreads();
  const int h = hb * 64 + (t & 63);
  const int jq = t >> 6;
  const float* wp = Wr + (size_t)(jq * 256) * 512 + h;
  float acc = 0.f;
#pragma unroll 8
  for (int k = 0; k < 256; ++k) acc += cpre[jq * 256 + k] * wp[(size_t)k * 512];
  part[jq][t & 63] = acc;
  __syncthreads();
  if (t < 64)
    out[b * 512 + hb * 64 + t] = part[0][t] + part[1][t] + part[2][t] + part[3][t];
}

extern "C" void kernel_launch(void* const* d_in, const int* in_sizes, int n_in, void* d_out,
                              int out_size, void* d_ws, size_t ws_size, hipStream_t stream) {
  const float* query = (const float*)d_in[0];     // (16,1,1024)
  const float* keys = (const float*)d_in[1];      // (16,2048,1024)
  const float* coverage = (const float*)d_in[2];  // (16,2048,1)
  const float* W1 = (const float*)d_in[3];        // (2049,1024)
  const float* b1 = (const float*)d_in[4];        // (1024,)
  const float* W2 = (const float*)d_in[5];        // (1024,1)
  const float* Wr = (const float*)d_in[6];        // (1024,512)
  float* out = (float*)d_out;
  char* ws = (char*)d_ws;

  float* scores_part = (float*)ws;          // 4*32768 f32 = 512KB @ 0
  float* ctx_part = (float*)(ws + 524288);  // 16*16*1024 f32 = 1MB
  float* qterm = (float*)(ws + 1638400);    // 16384 f32
  unsigned short* W1kt = (unsigned short*)(ws + 1703936);    // 1M bf16 (2MB)
  unsigned short* keysbf = (unsigned short*)(ws + 3801088);  // 32M bf16 (64MB)

  float* context_out = out;     // 16*512
  float* att_out = out + 8192;  // 16*2048

  prep_kernel<<<dim3(2560), dim3(256), 0, stream>>>(keys, keysbf, W1, W1kt, query, b1, qterm);
  gemm_score_v16<<<dim3(512), dim3(512), 0, stream>>>(keysbf, W1kt, qterm, coverage, W1, W2,
                                                      scores_part);
  ctxpre_fused<<<dim3(16, 16), dim3(256), 0, stream>>>(keysbf, scores_part, att_out, ctx_part);
  ctx2_kernel<<<dim3(8, 16), dim3(256), 0, stream>>>(ctx_part, Wr, context_out);
}